// Round 1
// baseline (785.433 us; speedup 1.0000x reference)
//
#include <hip/hip_runtime.h>
#include <hip/hip_bf16.h>

// GRNN tree transform, fp32 baseline.
// Levels: LEVEL_SIZES[j] = 64<<j, j=0..12. OFFSETS[j] = 64*(2^j-1) (rows).
// INNER_OFF[j] = 64*(2^j-1) (rows of children pairs).
// Per inner level: emb_j = tanh([emb_{j+1}[chL] | emb_{j+1}[chR] | u] @ w_h.T + b_h)
// u = tanh(c_j @ w_u.T + b_u).  Leaf level (j=12): emb = u.

#define NF 7
#define NH 128
#define KDIM 384
#define TM 32
#define KT 32
#define XS_STRIDE 388   // 384 + 4 pad; 388*4 bytes % 16 == 0 so float4 row starts stay aligned

__device__ __forceinline__ float ftanh(float x){
    // tanh(x) = 1 - 2/(exp(2x)+1); saturates correctly at +-inf, abs err ~1e-6
    float e = __expf(2.0f * x);
    return 1.0f - __fdividef(2.0f, e + 1.0f);
}

// w_hT[k][h] = w_h[h][k]; 49152 elements, 192 blocks of 256
__global__ __launch_bounds__(256) void k_transpose_w(const float* __restrict__ w_h,
                                                     float* __restrict__ w_hT){
    int idx = blockIdx.x * 256 + threadIdx.x;   // 0..49151
    int h = idx & (NH - 1);
    int k = idx >> 7;
    w_hT[(size_t)k * NH + h] = w_h[(size_t)h * KDIM + k];
}

// Leaf level: emb12[node][h] = tanh(b_u[h] + sum_f c[node][f]*w_u[h][f])
__global__ __launch_bounds__(256) void k_leaf(const float* __restrict__ contents,
                                              const float* __restrict__ w_u,
                                              const float* __restrict__ b_u,
                                              float* __restrict__ out){
    int idx = blockIdx.x * 256 + threadIdx.x;   // node*128 + h
    int node = idx >> 7;
    int h = idx & (NH - 1);
    const float* c = contents + (size_t)node * NF;
    const float* w = w_u + h * NF;
    float acc = b_u[h];
    #pragma unroll
    for (int f = 0; f < NF; ++f) acc = fmaf(c[f], w[f], acc);
    out[idx] = ftanh(acc);
}

// Inner level: TM=32 nodes per 256-thread block.
// xs[node][0:128]=hL, [128:256]=hR, [256:384]=u. GEMM vs w_hT staged K-tiles.
__global__ __launch_bounds__(256, 2) void k_inner(
    const float* __restrict__ contents,   // level-local base (node*7)
    const int2*  __restrict__ children,   // level-local base (node -> (L,R))
    const float* __restrict__ w_u,
    const float* __restrict__ b_u,
    const float* __restrict__ w_hT,       // [384][128]
    const float* __restrict__ b_h,
    const float* __restrict__ emb_next,   // [M*2][128]
    float*       __restrict__ out)        // [M][128]
{
    __shared__ float xs[TM][XS_STRIDE];   // 49664 B
    __shared__ float wt[KT][NH];          // 16384 B  -> total 64.5 KiB, 2 blocks/CU
    const int t = threadIdx.x;
    const int block0 = blockIdx.x * TM;

    // --- gather hL/hR: 32 nodes * 64 float4 = 2048 float4, 8 per thread ---
    #pragma unroll
    for (int q = 0; q < 8; ++q){
        int idx = q * 256 + t;
        int node = idx >> 6;          // 0..31
        int part = idx & 63;          // 0..31 -> hL cols, 32..63 -> hR cols
        int2 ch = children[block0 + node];
        int row = (part < 32) ? ch.x : ch.y;
        float4 v = ((const float4*)(emb_next + (size_t)row * NH))[part & 31];
        *(float4*)&xs[node][part * 4] = v;   // lane-contiguous LDS write
    }

    // --- u: 32 nodes * 128 = 4096 values, 16 per thread ---
    #pragma unroll
    for (int i = 0; i < 16; ++i){
        int e = i * 256 + t;
        int node = e >> 7;
        int col = e & (NH - 1);
        const float* c = contents + (size_t)(block0 + node) * NF;
        const float* w = w_u + col * NF;
        float acc = b_u[col];
        #pragma unroll
        for (int f = 0; f < NF; ++f) acc = fmaf(c[f], w[f], acc);
        xs[node][256 + col] = ftanh(acc);
    }

    float acc[4][4];
    #pragma unroll
    for (int n = 0; n < 4; ++n)
        #pragma unroll
        for (int j = 0; j < 4; ++j) acc[n][j] = 0.0f;

    const int tn = t >> 5;   // 0..7 -> nodes tn*4..tn*4+3
    const int th = t & 31;   // h = th*4..th*4+3

    for (int k0 = 0; k0 < KDIM; k0 += KT){
        __syncthreads();     // also covers gather/u on first iteration
        // stage wt[kk][h] = w_hT[k0+kk][h]: 1024 float4, 4 per thread, coalesced both sides
        #pragma unroll
        for (int r = 0; r < 4; ++r){
            int idx = r * 256 + t;
            int kk = idx >> 5;
            int hq = idx & 31;
            ((float4*)&wt[kk][0])[hq] = ((const float4*)(w_hT + (size_t)(k0 + kk) * NH))[hq];
        }
        __syncthreads();
        #pragma unroll
        for (int kk = 0; kk < KT; kk += 4){
            float4 wv0 = *(const float4*)&wt[kk + 0][th * 4];
            float4 wv1 = *(const float4*)&wt[kk + 1][th * 4];
            float4 wv2 = *(const float4*)&wt[kk + 2][th * 4];
            float4 wv3 = *(const float4*)&wt[kk + 3][th * 4];
            #pragma unroll
            for (int n = 0; n < 4; ++n){
                float4 xv = *(const float4*)&xs[tn * 4 + n][k0 + kk];
                acc[n][0] = fmaf(xv.x, wv0.x, acc[n][0]);
                acc[n][0] = fmaf(xv.y, wv1.x, acc[n][0]);
                acc[n][0] = fmaf(xv.z, wv2.x, acc[n][0]);
                acc[n][0] = fmaf(xv.w, wv3.x, acc[n][0]);
                acc[n][1] = fmaf(xv.x, wv0.y, acc[n][1]);
                acc[n][1] = fmaf(xv.y, wv1.y, acc[n][1]);
                acc[n][1] = fmaf(xv.z, wv2.y, acc[n][1]);
                acc[n][1] = fmaf(xv.w, wv3.y, acc[n][1]);
                acc[n][2] = fmaf(xv.x, wv0.z, acc[n][2]);
                acc[n][2] = fmaf(xv.y, wv1.z, acc[n][2]);
                acc[n][2] = fmaf(xv.z, wv2.z, acc[n][2]);
                acc[n][2] = fmaf(xv.w, wv3.z, acc[n][2]);
                acc[n][3] = fmaf(xv.x, wv0.w, acc[n][3]);
                acc[n][3] = fmaf(xv.y, wv1.w, acc[n][3]);
                acc[n][3] = fmaf(xv.z, wv2.w, acc[n][3]);
                acc[n][3] = fmaf(xv.w, wv3.w, acc[n][3]);
            }
        }
    }

    // --- epilogue: bias + tanh + coalesced float4 store ---
    #pragma unroll
    for (int n = 0; n < 4; ++n){
        int node = block0 + tn * 4 + n;
        float4 o;
        o.x = ftanh(acc[n][0] + b_h[th * 4 + 0]);
        o.y = ftanh(acc[n][1] + b_h[th * 4 + 1]);
        o.z = ftanh(acc[n][2] + b_h[th * 4 + 2]);
        o.w = ftanh(acc[n][3] + b_h[th * 4 + 3]);
        ((float4*)(out + (size_t)node * NH))[th] = o;
    }
}

extern "C" void kernel_launch(void* const* d_in, const int* in_sizes, int n_in,
                              void* d_out, int out_size, void* d_ws, size_t ws_size,
                              hipStream_t stream){
    const float* contents = (const float*)d_in[0];
    const int*   children = (const int*)d_in[1];
    const float* w_u      = (const float*)d_in[2];
    const float* b_u      = (const float*)d_in[3];
    const float* w_h      = (const float*)d_in[4];
    const float* b_h      = (const float*)d_in[5];
    float* out = (float*)d_out;

    // workspace layout: bufA (level 12,10,...: max 262144 rows) | bufB (11,9,...: max 131072) | w_hT
    // total = (262144+131072)*128*4 + 49152*4 = 201,523,200 bytes
    float* bufA = (float*)d_ws;
    float* bufB = bufA + (size_t)262144 * NH;
    float* w_hT = bufB + (size_t)131072 * NH;

    hipLaunchKernelGGL(k_transpose_w, dim3(192), dim3(256), 0, stream, w_h, w_hT);

    // leaf level j=12: 262144 nodes
    {
        size_t coff = (size_t)64 * ((1u << 12) - 1) * NF;
        hipLaunchKernelGGL(k_leaf, dim3((262144 * NH) / 256), dim3(256), 0, stream,
                           contents + coff, w_u, b_u, bufA);
    }

    for (int j = 11; j >= 0; --j){
        int M = 64 << j;
        size_t coff = (size_t)64 * ((1u << j) - 1) * NF;
        size_t chof = (size_t)64 * ((1u << j) - 1);
        const float* embN = ((j + 1) & 1) ? bufB : bufA;   // level j+1: even->A, odd->B
        float* o = (j == 0) ? out : ((j & 1) ? bufB : bufA);
        hipLaunchKernelGGL(k_inner, dim3(M / TM), dim3(256), 0, stream,
                           contents + coff, ((const int2*)children) + chof,
                           w_u, b_u, w_hT, b_h, embN, o);
    }
}

// Round 2
// 516.996 us; speedup vs baseline: 1.5192x; 1.5192x over previous
//
#include <hip/hip_runtime.h>
#include <hip/hip_bf16.h>

// GRNN tree transform, bf16-MFMA version.
// emb stored bf16 (identical GEMM numerics to fp32-store + convert-at-load).
// u precomputed for ALL nodes upfront (leaf u == emb_12).
// k_inner: per level j, emb_j = tanh([emb[chL]|emb[chR]|u] @ w_h.T + b_h)
//   as 3 uniform K-phases of 128 (hL, hR, u), 32x32x16 bf16 MFMA.

#define NF 7
#define NH 128
#define NIN 262080    // total inner nodes = 64*(2^12 - 1)
#define NLEAF 262144
#define XSTR 136      // 128 + 8 bf16 pad -> 272 B row stride (16B-aligned)

typedef __bf16 bf16;
typedef __bf16 bf16x8 __attribute__((ext_vector_type(8)));
typedef float floatx16 __attribute__((ext_vector_type(16)));

__device__ __forceinline__ float ftanh(float x){
    float e = __expf(2.0f * x);
    return 1.0f - __fdividef(2.0f, e + 1.0f);
}

__global__ __launch_bounds__(256) void k_wcast(const float* __restrict__ w,
                                               bf16* __restrict__ wb){
    int i = blockIdx.x * 256 + threadIdx.x;   // 49152 elements
    wb[i] = (bf16)w[i];
}

// u[node][col] = tanh(b_u[col] + contents[node] . w_u[col]) for all 524224 nodes.
// node < NIN -> u_all, else -> embA (leaf emb). 2 cols per thread, packed store.
__global__ __launch_bounds__(256) void k_u_all(const float* __restrict__ contents,
        const float* __restrict__ w_u, const float* __restrict__ b_u,
        bf16* __restrict__ u_all, bf16* __restrict__ embA){
    long long e = ((long long)blockIdx.x * 256 + threadIdx.x) * 2;
    int node = (int)(e >> 7);
    int col  = (int)(e & 127);
    const float* c  = contents + (size_t)node * NF;
    const float* w0 = w_u + (size_t)col * NF;
    const float* w1 = w0 + NF;
    float a0 = b_u[col], a1 = b_u[col + 1];
    #pragma unroll
    for (int f = 0; f < NF; ++f){
        float cf = c[f];
        a0 = fmaf(cf, w0[f], a0);
        a1 = fmaf(cf, w1[f], a1);
    }
    union { unsigned int u; bf16 h[2]; } pk;
    pk.h[0] = (bf16)ftanh(a0);
    pk.h[1] = (bf16)ftanh(a1);
    if (node < NIN) ((unsigned int*)u_all)[e >> 1] = pk.u;
    else ((unsigned int*)embA)[(e - (long long)NIN * NH) >> 1] = pk.u;
}

// Block: 256 threads (4 waves), tile 128 nodes x 128 cols, K=384 as 3 phases of 128.
// Wave w: node-tiles {(w&1)*2, +1}, col-tiles {(w>>1)*2, +1} (32x32 each).
__global__ __launch_bounds__(256, 2) void k_inner(
    const int2* __restrict__ children,    // level-local
    const bf16* __restrict__ u_level,     // u_all + level base, [M][128]
    const bf16* __restrict__ wb,          // w_h bf16 [128][384] (row-major, k contig)
    const float* __restrict__ b_h,
    const bf16* __restrict__ emb_next,    // [2M][128]
    bf16*       __restrict__ out_b,       // level j>0 output
    float*      __restrict__ out_f,       // level j==0 output (d_out)
    int M, int f32out)
{
    __shared__ bf16 xs[128 * XSTR];       // 34816 B
    __shared__ bf16 wt[128 * XSTR];       // 34816 B
    __shared__ int2 ch_s[128];            // 1024 B  -> 70656 B total, 2 blocks/CU

    const int t = threadIdx.x;
    const int block0 = blockIdx.x * 128;

    if (t < 128){
        int g = block0 + t;
        if (g > M - 1) g = M - 1;
        ch_s[t] = children[g];
    }

    const int lane = t & 63;
    const int wv   = t >> 6;
    const int m    = lane & 31;
    const int q    = lane >> 5;           // 0/1
    const int nt0  = (wv & 1) * 2;        // node-tile base
    const int ct0  = (wv >> 1) * 2;       // col-tile base

    floatx16 acc00 = {0,0,0,0,0,0,0,0,0,0,0,0,0,0,0,0};
    floatx16 acc01 = {0,0,0,0,0,0,0,0,0,0,0,0,0,0,0,0};
    floatx16 acc10 = {0,0,0,0,0,0,0,0,0,0,0,0,0,0,0,0};
    floatx16 acc11 = {0,0,0,0,0,0,0,0,0,0,0,0,0,0,0,0};

    #pragma unroll 1
    for (int p = 0; p < 3; ++p){
        __syncthreads();   // protects ch_s (p==0) and previous phase's reads
        // --- stage xs: 128 nodes x 128 bf16 = 2048 x 16B, 8 per thread ---
        #pragma unroll
        for (int q8 = 0; q8 < 8; ++q8){
            int task = q8 * 256 + t;
            int i = task >> 4, part = task & 15;
            const bf16* src;
            if (p == 0)      src = emb_next + (size_t)ch_s[i].x * NH;
            else if (p == 1) src = emb_next + (size_t)ch_s[i].y * NH;
            else {
                int g = block0 + i; if (g > M - 1) g = M - 1;
                src = u_level + (size_t)g * NH;
            }
            uint4 v = *(const uint4*)(src + part * 8);
            *(uint4*)&xs[i * XSTR + part * 8] = v;
        }
        // --- stage wt: wb[:, p*128 : p*128+128] ---
        const bf16* wsrc = wb + p * 128;
        #pragma unroll
        for (int q8 = 0; q8 < 8; ++q8){
            int task = q8 * 256 + t;
            int n = task >> 4, part = task & 15;
            uint4 v = *(const uint4*)(wsrc + (size_t)n * 384 + part * 8);
            *(uint4*)&wt[n * XSTR + part * 8] = v;
        }
        __syncthreads();
        // --- 8 MFMA k-steps of 16 ---
        const bf16* xa = &xs[(nt0 * 32 + m) * XSTR + q * 8];
        const bf16* xb = &wt[(ct0 * 32 + m) * XSTR + q * 8];
        #pragma unroll
        for (int kk = 0; kk < 8; ++kk){
            bf16x8 a0 = *(const bf16x8*)(xa + kk * 16);
            bf16x8 a1 = *(const bf16x8*)(xa + kk * 16 + 32 * XSTR);
            bf16x8 b0 = *(const bf16x8*)(xb + kk * 16);
            bf16x8 b1 = *(const bf16x8*)(xb + kk * 16 + 32 * XSTR);
            acc00 = __builtin_amdgcn_mfma_f32_32x32x16_bf16(a0, b0, acc00, 0, 0, 0);
            acc01 = __builtin_amdgcn_mfma_f32_32x32x16_bf16(a0, b1, acc01, 0, 0, 0);
            acc10 = __builtin_amdgcn_mfma_f32_32x32x16_bf16(a1, b0, acc10, 0, 0, 0);
            acc11 = __builtin_amdgcn_mfma_f32_32x32x16_bf16(a1, b1, acc11, 0, 0, 0);
        }
    }

    // --- epilogue: bias + tanh + store (C/D: col=lane&31, row=(r&3)+8*(r>>2)+4*q) ---
    #pragma unroll
    for (int a = 0; a < 2; ++a){
        #pragma unroll
        for (int b = 0; b < 2; ++b){
            const floatx16* accp = (a == 0) ? ((b == 0) ? &acc00 : &acc01)
                                            : ((b == 0) ? &acc10 : &acc11);
            int colg = (ct0 + b) * 32 + m;
            float bv = b_h[colg];
            #pragma unroll
            for (int r = 0; r < 16; ++r){
                int row  = (r & 3) + 8 * (r >> 2) + 4 * q;
                int node = block0 + (nt0 + a) * 32 + row;
                if (node < M){
                    float v = ftanh((*accp)[r] + bv);
                    if (f32out) out_f[(size_t)node * NH + colg] = v;
                    else        out_b[(size_t)node * NH + colg] = (bf16)v;
                }
            }
        }
    }
}

extern "C" void kernel_launch(void* const* d_in, const int* in_sizes, int n_in,
                              void* d_out, int out_size, void* d_ws, size_t ws_size,
                              hipStream_t stream){
    const float* contents = (const float*)d_in[0];
    const int*   children = (const int*)d_in[1];
    const float* w_u      = (const float*)d_in[2];
    const float* b_u      = (const float*)d_in[3];
    const float* w_h      = (const float*)d_in[4];
    const float* b_h      = (const float*)d_in[5];

    // ws layout (bf16): u_all [NIN][128] | embA [NLEAF][128] | embB [131072][128] | wb [128][384]
    bf16* u_all = (bf16*)d_ws;
    bf16* embA  = u_all + (size_t)NIN * NH;
    bf16* embB  = embA + (size_t)NLEAF * NH;
    bf16* wb    = embB + (size_t)131072 * NH;
    // total = 167,854,080 bytes

    hipLaunchKernelGGL(k_wcast, dim3(192), dim3(256), 0, stream, w_h, wb);
    hipLaunchKernelGGL(k_u_all, dim3(131056), dim3(256), 0, stream,
                       contents, w_u, b_u, u_all, embA);

    for (int j = 11; j >= 0; --j){
        int M = 64 << j;
        size_t lvl = (size_t)64 * ((1u << j) - 1);       // INNER_OFF[j] rows
        const bf16* embN = ((j + 1) == 12) ? embA : (((j + 1) & 1) ? embB : embA);
        bf16* ob = (j & 1) ? embB : embA;
        hipLaunchKernelGGL(k_inner, dim3((M + 127) / 128), dim3(256), 0, stream,
                           ((const int2*)children) + lvl,
                           u_all + lvl * NH, wb, b_h, embN,
                           (j == 0) ? (bf16*)nullptr : ob,
                           (j == 0) ? (float*)d_out : (float*)nullptr,
                           M, (j == 0) ? 1 : 0);
    }
}

// Round 3
// 414.595 us; speedup vs baseline: 1.8945x; 1.2470x over previous
//
#include <hip/hip_runtime.h>
#include <hip/hip_bf16.h>

// GRNN tree transform, bf16-MFMA, u fused into the level kernel.
// emb stored bf16. Leaf emb (= u of leaves) via dedicated write-bound kernel.
// k_inner: per level j, emb_j = tanh([emb[chL]|emb[chR]|u] @ w_h.T + b_h)
//   3 K-phases of 128 (hL gather, hR gather, u computed in-kernel), 32x32x16 MFMA.

#define NF 7
#define NH 128
#define NLEAF 262144
#define XSTR 136      // 128 + 8 bf16 pad -> 272 B row stride (16B-aligned)

typedef __bf16 bf16;
typedef __bf16 bf16x8 __attribute__((ext_vector_type(8)));
typedef float floatx16 __attribute__((ext_vector_type(16)));

__device__ __forceinline__ float ftanh(float x){
    float e = __expf(2.0f * x);
    return 1.0f - __fdividef(2.0f, e + 1.0f);
}

__global__ __launch_bounds__(256) void k_wcast(const float* __restrict__ w,
                                               bf16* __restrict__ wb){
    int i = blockIdx.x * 256 + threadIdx.x;   // 49152 elements
    wb[i] = (bf16)w[i];
}

// Leaf level: embA[node][col] = tanh(b_u + c_leaf[node] . w_u[col]).
// Wave layout: lane = col-pair (2l, 2l+1), 16 nodes per wave, w_u in registers,
// contents loads are wave-uniform (1 transaction), stores 256 B coalesced.
__global__ __launch_bounds__(256) void k_leaf(const float* __restrict__ contents_leaf,
        const float* __restrict__ w_u, const float* __restrict__ b_u,
        unsigned int* __restrict__ embA_u32){
    const int t = threadIdx.x;
    const int l = t & 63;
    const int wv = t >> 6;
    const int node0 = blockIdx.x * 64 + wv * 16;

    float wu0[NF], wu1[NF];
    const float* w0 = w_u + (size_t)(2 * l) * NF;
    #pragma unroll
    for (int f = 0; f < NF; ++f){ wu0[f] = w0[f]; wu1[f] = w0[NF + f]; }
    const float bu0 = b_u[2 * l], bu1 = b_u[2 * l + 1];

    #pragma unroll 4
    for (int i = 0; i < 16; ++i){
        int node = node0 + i;
        const float* c = contents_leaf + (size_t)node * NF;
        float a0 = bu0, a1 = bu1;
        #pragma unroll
        for (int f = 0; f < NF; ++f){
            float cf = c[f];
            a0 = fmaf(cf, wu0[f], a0);
            a1 = fmaf(cf, wu1[f], a1);
        }
        union { unsigned int u; bf16 h[2]; } pk;
        pk.h[0] = (bf16)ftanh(a0);
        pk.h[1] = (bf16)ftanh(a1);
        embA_u32[(size_t)node * 64 + l] = pk.u;
    }
}

// Block: 256 threads (4 waves), tile 128 nodes x 128 cols, K=384 as 3 phases.
// Wave w: node-tiles {(w&1)*2,+1}, col-tiles {(w>>1)*2,+1} (32x32 each).
__global__ __launch_bounds__(256, 2) void k_inner(
    const int2* __restrict__ children,    // level-local
    const float* __restrict__ contents,   // level-local (node*7)
    const float* __restrict__ w_u,
    const float* __restrict__ b_u,
    const bf16* __restrict__ wb,          // w_h bf16 [128][384]
    const float* __restrict__ b_h,
    const bf16* __restrict__ emb_next,    // [2M][128]
    bf16*       __restrict__ out_b,
    float*      __restrict__ out_f,
    int M, int f32out)
{
    __shared__ bf16 xs[128 * XSTR];       // 34816 B
    __shared__ bf16 wt[128 * XSTR];       // 34816 B
    __shared__ int2 ch_s[128];            // -> 70656 B total, 2 blocks/CU

    const int t = threadIdx.x;
    const int block0 = blockIdx.x * 128;

    if (t < 128){
        int g = block0 + t;
        if (g > M - 1) g = M - 1;
        ch_s[t] = children[g];
    }

    // per-thread w_u col-pair registers for the fused u phase
    const int cp = t & 63;                // col pair: cols 2cp, 2cp+1
    const int wvid = t >> 6;
    float wu0[NF], wu1[NF];
    {
        const float* w0 = w_u + (size_t)(2 * cp) * NF;
        #pragma unroll
        for (int f = 0; f < NF; ++f){ wu0[f] = w0[f]; wu1[f] = w0[NF + f]; }
    }
    const float bu0 = b_u[2 * cp], bu1 = b_u[2 * cp + 1];

    const int lane = t & 63;
    const int wv   = t >> 6;
    const int m    = lane & 31;
    const int q    = lane >> 5;
    const int nt0  = (wv & 1) * 2;
    const int ct0  = (wv >> 1) * 2;

    floatx16 acc00 = {0,0,0,0,0,0,0,0,0,0,0,0,0,0,0,0};
    floatx16 acc01 = {0,0,0,0,0,0,0,0,0,0,0,0,0,0,0,0};
    floatx16 acc10 = {0,0,0,0,0,0,0,0,0,0,0,0,0,0,0,0};
    floatx16 acc11 = {0,0,0,0,0,0,0,0,0,0,0,0,0,0,0,0};

    #pragma unroll 1
    for (int p = 0; p < 3; ++p){
        __syncthreads();   // protects ch_s (p==0) and previous phase's LDS reads
        if (p < 2){
            // gather hL (p=0) or hR (p=1): 2048 x 16B, 8 per thread
            #pragma unroll
            for (int q8 = 0; q8 < 8; ++q8){
                int task = q8 * 256 + t;
                int i = task >> 4, part = task & 15;
                int row = (p == 0) ? ch_s[i].x : ch_s[i].y;
                uint4 v = *(const uint4*)(emb_next + (size_t)row * NH + part * 8);
                *(uint4*)&xs[i * XSTR + part * 8] = v;
            }
        } else {
            // fused u: each thread computes cols (2cp,2cp+1) for 32 nodes
            #pragma unroll 4
            for (int i = 0; i < 32; ++i){
                int node = wvid * 32 + i;
                int g = block0 + node; if (g > M - 1) g = M - 1;
                const float* c = contents + (size_t)g * NF;
                float a0 = bu0, a1 = bu1;
                #pragma unroll
                for (int f = 0; f < NF; ++f){
                    float cf = c[f];
                    a0 = fmaf(cf, wu0[f], a0);
                    a1 = fmaf(cf, wu1[f], a1);
                }
                union { unsigned int u; bf16 h[2]; } pk;
                pk.h[0] = (bf16)ftanh(a0);
                pk.h[1] = (bf16)ftanh(a1);
                ((unsigned int*)xs)[node * (XSTR / 2) + cp] = pk.u;
            }
        }
        // stage wt: wb[:, p*128 : p*128+128]
        const bf16* wsrc = wb + p * 128;
        #pragma unroll
        for (int q8 = 0; q8 < 8; ++q8){
            int task = q8 * 256 + t;
            int n = task >> 4, part = task & 15;
            uint4 v = *(const uint4*)(wsrc + (size_t)n * 384 + part * 8);
            *(uint4*)&wt[n * XSTR + part * 8] = v;
        }
        __syncthreads();
        // 8 MFMA k-steps of 16
        const bf16* xa = &xs[(nt0 * 32 + m) * XSTR + q * 8];
        const bf16* xb = &wt[(ct0 * 32 + m) * XSTR + q * 8];
        #pragma unroll
        for (int kk = 0; kk < 8; ++kk){
            bf16x8 a0 = *(const bf16x8*)(xa + kk * 16);
            bf16x8 a1 = *(const bf16x8*)(xa + kk * 16 + 32 * XSTR);
            bf16x8 b0 = *(const bf16x8*)(xb + kk * 16);
            bf16x8 b1 = *(const bf16x8*)(xb + kk * 16 + 32 * XSTR);
            acc00 = __builtin_amdgcn_mfma_f32_32x32x16_bf16(a0, b0, acc00, 0, 0, 0);
            acc01 = __builtin_amdgcn_mfma_f32_32x32x16_bf16(a0, b1, acc01, 0, 0, 0);
            acc10 = __builtin_amdgcn_mfma_f32_32x32x16_bf16(a1, b0, acc10, 0, 0, 0);
            acc11 = __builtin_amdgcn_mfma_f32_32x32x16_bf16(a1, b1, acc11, 0, 0, 0);
        }
    }

    // epilogue: bias + tanh + store (C/D: col=lane&31, row=(r&3)+8*(r>>2)+4*q)
    #pragma unroll
    for (int a = 0; a < 2; ++a){
        #pragma unroll
        for (int b = 0; b < 2; ++b){
            const floatx16* accp = (a == 0) ? ((b == 0) ? &acc00 : &acc01)
                                            : ((b == 0) ? &acc10 : &acc11);
            int colg = (ct0 + b) * 32 + m;
            float bv = b_h[colg];
            #pragma unroll
            for (int r = 0; r < 16; ++r){
                int row  = (r & 3) + 8 * (r >> 2) + 4 * q;
                int node = block0 + (nt0 + a) * 32 + row;
                if (node < M){
                    float v = ftanh((*accp)[r] + bv);
                    if (f32out) out_f[(size_t)node * NH + colg] = v;
                    else        out_b[(size_t)node * NH + colg] = (bf16)v;
                }
            }
        }
    }
}

extern "C" void kernel_launch(void* const* d_in, const int* in_sizes, int n_in,
                              void* d_out, int out_size, void* d_ws, size_t ws_size,
                              hipStream_t stream){
    const float* contents = (const float*)d_in[0];
    const int*   children = (const int*)d_in[1];
    const float* w_u      = (const float*)d_in[2];
    const float* b_u      = (const float*)d_in[3];
    const float* w_h      = (const float*)d_in[4];
    const float* b_h      = (const float*)d_in[5];

    // ws layout (bf16): embA [262144][128] | embB [131072][128] | wb [128][384]
    bf16* embA = (bf16*)d_ws;
    bf16* embB = embA + (size_t)NLEAF * NH;
    bf16* wb   = embB + (size_t)131072 * NH;
    // total = 100,761,600 bytes

    hipLaunchKernelGGL(k_wcast, dim3(192), dim3(256), 0, stream, w_h, wb);
    // leaf level j=12: contents offset 64*(2^12-1)*7
    hipLaunchKernelGGL(k_leaf, dim3(NLEAF / 64), dim3(256), 0, stream,
                       contents + (size_t)262080 * NF, w_u, b_u, (unsigned int*)embA);

    for (int j = 11; j >= 0; --j){
        int M = 64 << j;
        size_t lvl = (size_t)64 * ((1u << j) - 1);       // level-local base (rows)
        const bf16* embN = ((j + 1) == 12) ? embA : (((j + 1) & 1) ? embB : embA);
        bf16* ob = (j & 1) ? embB : embA;
        hipLaunchKernelGGL(k_inner, dim3((M + 127) / 128), dim3(256), 0, stream,
                           ((const int2*)children) + lvl,
                           contents + lvl * NF, w_u, b_u, wb, b_h, embN,
                           (j == 0) ? (bf16*)nullptr : ob,
                           (j == 0) ? (float*)d_out : (float*)nullptr,
                           M, (j == 0) ? 1 : 0);
    }
}

// Round 4
// 285.153 us; speedup vs baseline: 2.7544x; 1.4539x over previous
//
#include <hip/hip_runtime.h>
#include <hip/hip_bf16.h>

// GRNN tree transform, bf16-MFMA v3.
// - 64-node blocks (always exactly full: no bounds checks anywhere)
// - B (w_h) fragments loaded per-phase straight from global (L2-hot) into VGPRs;
//   no wt LDS buffer -> LDS ~20 KB -> 4 blocks/CU
// - contents staged via LDS (coalesced) for the fused u phase and for k_leaf
// emb stored bf16; identical numerics to round 2/3 (absmax 5.9e-3).

#define NF 7
#define NH 128
#define NLEAF 262144
#define XSTR 136      // 128 + 8 bf16 pad; row stride 272 B (16B-aligned)

typedef __bf16 bf16;
typedef __bf16 bf16x8 __attribute__((ext_vector_type(8)));
typedef float floatx16 __attribute__((ext_vector_type(16)));

__device__ __forceinline__ float ftanh(float x){
    float e = __expf(2.0f * x);
    return 1.0f - __fdividef(2.0f, e + 1.0f);
}

__global__ __launch_bounds__(256) void k_wcast(const float* __restrict__ w,
                                               bf16* __restrict__ wb){
    int i = blockIdx.x * 256 + threadIdx.x;   // 49152 elements
    wb[i] = (bf16)w[i];
}

// Leaf level: 128 nodes/block, contents staged to LDS (coalesced), w_u in regs.
// Thread: col-pair cp = t&63, nodes (t>>6)*32 + i. Stores 256B-coalesced dwords.
__global__ __launch_bounds__(256) void k_leaf(const float* __restrict__ contents_leaf,
        const float* __restrict__ w_u, const float* __restrict__ b_u,
        unsigned int* __restrict__ embA_u32){
    __shared__ float cs[128 * 8];             // padded rows of 8
    const int t = threadIdx.x;
    const int block0 = blockIdx.x * 128;

    // stage 128*7 = 896 floats = 224 float4, scatter 7->8 padded rows
    if (t < 224){
        float4 v = ((const float4*)(contents_leaf + (size_t)block0 * NF))[t];
        int e = t * 4;
        float vv[4] = {v.x, v.y, v.z, v.w};
        #pragma unroll
        for (int r = 0; r < 4; ++r){
            int ee = e + r;
            cs[(ee / 7) * 8 + (ee % 7)] = vv[r];
        }
    }

    const int cp = t & 63;
    const int quarter = t >> 6;
    float wu0[NF], wu1[NF];
    const float* w0 = w_u + (size_t)(2 * cp) * NF;
    #pragma unroll
    for (int f = 0; f < NF; ++f){ wu0[f] = w0[f]; wu1[f] = w0[NF + f]; }
    const float bu0 = b_u[2 * cp], bu1 = b_u[2 * cp + 1];

    __syncthreads();

    #pragma unroll 4
    for (int i = 0; i < 32; ++i){
        int node = quarter * 32 + i;
        float4 c0 = *(const float4*)&cs[node * 8];
        float4 c1 = *(const float4*)&cs[node * 8 + 4];
        float a0 = bu0, a1 = bu1;
        a0 = fmaf(c0.x, wu0[0], a0); a1 = fmaf(c0.x, wu1[0], a1);
        a0 = fmaf(c0.y, wu0[1], a0); a1 = fmaf(c0.y, wu1[1], a1);
        a0 = fmaf(c0.z, wu0[2], a0); a1 = fmaf(c0.z, wu1[2], a1);
        a0 = fmaf(c0.w, wu0[3], a0); a1 = fmaf(c0.w, wu1[3], a1);
        a0 = fmaf(c1.x, wu0[4], a0); a1 = fmaf(c1.x, wu1[4], a1);
        a0 = fmaf(c1.y, wu0[5], a0); a1 = fmaf(c1.y, wu1[5], a1);
        a0 = fmaf(c1.z, wu0[6], a0); a1 = fmaf(c1.z, wu1[6], a1);
        union { unsigned int u; bf16 h[2]; } pk;
        pk.h[0] = (bf16)ftanh(a0);
        pk.h[1] = (bf16)ftanh(a1);
        embA_u32[(size_t)(block0 + node) * 64 + cp] = pk.u;
    }
}

// Inner level: 64 nodes x 128 cols per block, K=384 in 3 phases of 128.
// Wave wv owns col-tile wv (32 cols), iterates node-tiles {0,1}.
// B-frags: 8 x bf16x8 from global per phase (L2-hot w_h), reused by both node-tiles.
__global__ __launch_bounds__(256, 4) void k_inner(
    const int2* __restrict__ children,    // level-local
    const float* __restrict__ contents,   // level-local (node*7)
    const float* __restrict__ w_u,
    const float* __restrict__ b_u,
    const bf16* __restrict__ wb,          // w_h bf16 [128][384]
    const float* __restrict__ b_h,
    const bf16* __restrict__ emb_next,    // [2M][128]
    bf16*       __restrict__ out_b,
    float*      __restrict__ out_f,
    int f32out)
{
    __shared__ bf16 xs[64 * XSTR];        // 17408 B
    __shared__ int2 ch_s[64];             // 512 B
    __shared__ float cs[64 * 8];          // 2048 B   -> ~20 KB total, 4 blocks/CU

    const int t = threadIdx.x;
    const int block0 = blockIdx.x * 64;

    if (t < 64) ch_s[t] = children[block0 + t];
    if (t < 112){   // 64*7 = 448 floats = 112 float4, scatter to padded rows
        float4 v = ((const float4*)(contents + (size_t)block0 * NF))[t];
        int e = t * 4;
        float vv[4] = {v.x, v.y, v.z, v.w};
        #pragma unroll
        for (int r = 0; r < 4; ++r){
            int ee = e + r;
            cs[(ee / 7) * 8 + (ee % 7)] = vv[r];
        }
    }

    const int cp = t & 63;                // col-pair for the u phase
    const int quarter = t >> 6;
    float wu0[NF], wu1[NF];
    {
        const float* w0 = w_u + (size_t)(2 * cp) * NF;
        #pragma unroll
        for (int f = 0; f < NF; ++f){ wu0[f] = w0[f]; wu1[f] = w0[NF + f]; }
    }
    const float bu0 = b_u[2 * cp], bu1 = b_u[2 * cp + 1];

    const int lane = t & 63;
    const int ct   = t >> 6;              // col-tile = wave id
    const int m    = lane & 31;
    const int q    = lane >> 5;

    floatx16 acc0 = {0,0,0,0,0,0,0,0,0,0,0,0,0,0,0,0};
    floatx16 acc1 = {0,0,0,0,0,0,0,0,0,0,0,0,0,0,0,0};

    const bf16* bq = wb + ((size_t)(ct * 32 + m) * 384 + q * 8);

    #pragma unroll 1
    for (int p = 0; p < 3; ++p){
        __syncthreads();   // prev phase's xs reads done; ch_s/cs visible at p=0
        if (p < 2){
            // gather hL (p=0) / hR (p=1): 64 rows x 256 B = 1024 x 16 B, 4/thread
            #pragma unroll
            for (int r = 0; r < 4; ++r){
                int task = r * 256 + t;
                int i = task >> 4, part = task & 15;
                int row = (p == 0) ? ch_s[i].x : ch_s[i].y;
                uint4 v = *(const uint4*)(emb_next + (size_t)row * NH + part * 8);
                *(uint4*)&xs[i * XSTR + part * 8] = v;
            }
        } else {
            // fused u: thread covers cols (2cp,2cp+1) for 16 nodes
            #pragma unroll 4
            for (int i = 0; i < 16; ++i){
                int node = quarter * 16 + i;
                float4 c0 = *(const float4*)&cs[node * 8];
                float4 c1 = *(const float4*)&cs[node * 8 + 4];
                float a0 = bu0, a1 = bu1;
                a0 = fmaf(c0.x, wu0[0], a0); a1 = fmaf(c0.x, wu1[0], a1);
                a0 = fmaf(c0.y, wu0[1], a0); a1 = fmaf(c0.y, wu1[1], a1);
                a0 = fmaf(c0.z, wu0[2], a0); a1 = fmaf(c0.z, wu1[2], a1);
                a0 = fmaf(c0.w, wu0[3], a0); a1 = fmaf(c0.w, wu1[3], a1);
                a0 = fmaf(c1.x, wu0[4], a0); a1 = fmaf(c1.x, wu1[4], a1);
                a0 = fmaf(c1.y, wu0[5], a0); a1 = fmaf(c1.y, wu1[5], a1);
                a0 = fmaf(c1.z, wu0[6], a0); a1 = fmaf(c1.z, wu1[6], a1);
                union { unsigned int u; bf16 h[2]; } pk;
                pk.h[0] = (bf16)ftanh(a0);
                pk.h[1] = (bf16)ftanh(a1);
                ((unsigned int*)xs)[node * (XSTR / 2) + cp] = pk.u;
            }
        }
        // B-frags for this phase: 8 x 16 B from global (L2-hot), reused 2x
        bf16x8 bfr[8];
        #pragma unroll
        for (int kk = 0; kk < 8; ++kk)
            bfr[kk] = *(const bf16x8*)(bq + p * 128 + kk * 16);

        __syncthreads();   // xs ready
        const bf16* xa = &xs[m * XSTR + q * 8];
        #pragma unroll
        for (int kk = 0; kk < 8; ++kk){
            bf16x8 a0 = *(const bf16x8*)(xa + kk * 16);
            bf16x8 a1 = *(const bf16x8*)(xa + kk * 16 + 32 * XSTR);
            acc0 = __builtin_amdgcn_mfma_f32_32x32x16_bf16(a0, bfr[kk], acc0, 0, 0, 0);
            acc1 = __builtin_amdgcn_mfma_f32_32x32x16_bf16(a1, bfr[kk], acc1, 0, 0, 0);
        }
    }

    // epilogue: bias + tanh + store. C/D: col = lane&31, row = (r&3)+8*(r>>2)+4*q.
    const int colg = ct * 32 + m;
    const float bv = b_h[colg];
    if (f32out){
        #pragma unroll
        for (int nt = 0; nt < 2; ++nt){
            const floatx16* accp = nt ? &acc1 : &acc0;
            #pragma unroll
            for (int r = 0; r < 16; ++r){
                int row  = (r & 3) + 8 * (r >> 2) + 4 * q;
                int node = block0 + nt * 32 + row;
                out_f[(size_t)node * NH + colg] = ftanh((*accp)[r] + bv);
            }
        }
    } else {
        #pragma unroll
        for (int nt = 0; nt < 2; ++nt){
            const floatx16* accp = nt ? &acc1 : &acc0;
            #pragma unroll
            for (int r = 0; r < 16; ++r){
                int row  = (r & 3) + 8 * (r >> 2) + 4 * q;
                int node = block0 + nt * 32 + row;
                out_b[(size_t)node * NH + colg] = (bf16)ftanh((*accp)[r] + bv);
            }
        }
    }
}

extern "C" void kernel_launch(void* const* d_in, const int* in_sizes, int n_in,
                              void* d_out, int out_size, void* d_ws, size_t ws_size,
                              hipStream_t stream){
    const float* contents = (const float*)d_in[0];
    const int*   children = (const int*)d_in[1];
    const float* w_u      = (const float*)d_in[2];
    const float* b_u      = (const float*)d_in[3];
    const float* w_h      = (const float*)d_in[4];
    const float* b_h      = (const float*)d_in[5];

    // ws layout (bf16): embA [262144][128] | embB [131072][128] | wb [128][384]
    bf16* embA = (bf16*)d_ws;
    bf16* embB = embA + (size_t)NLEAF * NH;
    bf16* wb   = embB + (size_t)131072 * NH;
    // total ~100.8 MB

    hipLaunchKernelGGL(k_wcast, dim3(192), dim3(256), 0, stream, w_h, wb);
    // leaf level j=12: contents row offset 64*(2^12-1) = 262080
    hipLaunchKernelGGL(k_leaf, dim3(NLEAF / 128), dim3(256), 0, stream,
                       contents + (size_t)262080 * NF, w_u, b_u, (unsigned int*)embA);

    for (int j = 11; j >= 0; --j){
        int M = 64 << j;
        size_t lvl = (size_t)64 * ((1u << j) - 1);       // level-local base (rows)
        const bf16* embN = ((j + 1) & 1) ? embB : embA;  // level 12 is even -> embA
        bf16* ob = (j & 1) ? embB : embA;
        hipLaunchKernelGGL(k_inner, dim3(M / 64), dim3(256), 0, stream,
                           ((const int2*)children) + lvl,
                           contents + lvl * NF, w_u, b_u, wb, b_h, embN,
                           (j == 0) ? (bf16*)nullptr : ob,
                           (j == 0) ? (float*)d_out : (float*)nullptr,
                           (j == 0) ? 1 : 0);
    }
}